// Round 1
// baseline (301.894 us; speedup 1.0000x reference)
//
#include <hip/hip_runtime.h>
#include <hip/hip_bf16.h>
#include <stdint.h>

// ---------------- problem constants ----------------
#define NB   32
#define NC   256
#define NOC  256
#define HWD  56
#define NPIX 3136      // 56*56
#define PW   58        // padded row width
#define PPIX 3364      // 58*58
#define KTOT 2304      // 9 * 256
#define MOD  512       // fc1 out channels
#define GAPD 16

// workspace layout (bytes)
#define XBT_BYTES ((size_t)NB * PPIX * NC * 2)            // 55,115,776
#define WA_BYTES  ((size_t)NB * NOC * KTOT * 2)           // 37,748,736

typedef __bf16 bf16x8 __attribute__((ext_vector_type(8)));
typedef float  f32x4  __attribute__((ext_vector_type(4)));
typedef unsigned short u16x8 __attribute__((ext_vector_type(8)));

__device__ __forceinline__ unsigned short f2bf(float f) {
    union { float f; unsigned int u; } v; v.f = f;
    unsigned int u = v.u;
    return (unsigned short)((u + 0x7FFFu + ((u >> 16) & 1u)) >> 16);
}

// ---------------- P1: global average pool ----------------
// one wave per (b,c); grid 2048 x 256 threads
__global__ void gap_kernel(const float* __restrict__ x, float* __restrict__ gap) {
    int bc = blockIdx.x * 4 + (threadIdx.x >> 6);
    int l  = threadIdx.x & 63;
    const float* p = x + (size_t)bc * NPIX;
    float s = 0.f;
    #pragma unroll
    for (int k = 0; k < 49; ++k) s += p[l + k * 64];
    #pragma unroll
    for (int off = 32; off > 0; off >>= 1) s += __shfl_down(s, off, 64);
    if (l == 0) gap[bc] = s * (1.0f / NPIX);
}

// ---------------- P2: SE network (one block, 512 threads) ----------------
__global__ void se_kernel(const float* __restrict__ gap,
                          const float* __restrict__ rw, const float* __restrict__ rb,
                          const float* __restrict__ f1w, float* __restrict__ a2) {
    __shared__ float sgap[NB * NC];
    __shared__ float sg[NB * GAPD];
    int t = threadIdx.x; // 0..511
    #pragma unroll
    for (int i = 0; i < 16; ++i) sgap[i * 512 + t] = gap[i * 512 + t];
    __syncthreads();
    {
        int b = t >> 4, tt = t & 15;
        float s = rb[tt];
        for (int c = 0; c < NC; ++c) s += sgap[b * NC + c] * rw[tt * NC + c];
        sg[b * GAPD + tt] = s;
    }
    __syncthreads();
    for (int i = 0; i < 32; ++i) {
        int o = i * 512 + t;
        int b = o >> 9, m = o & 511;
        float s = 0.f;
        #pragma unroll
        for (int tt = 0; tt < GAPD; ++tt) s += sg[b * GAPD + tt] * f1w[m * GAPD + tt];
        a2[o] = 1.0f / (1.0f + __expf(-s));
    }
}

// ---------------- P3: materialize per-batch conv weights, bf16, k = s*256+c ----------------
// grid (256 oc, 32 b) x 256 threads (t = c)
__global__ void wk_kernel(const float* __restrict__ a2,
                          const float* __restrict__ f2w, const float* __restrict__ f2b,
                          unsigned short* __restrict__ wa) {
    int oc = blockIdx.x, b = blockIdx.y, c = threadIdx.x;
    float a0 = a2[b * MOD + 2 * oc];
    float a1 = a2[b * MOD + 2 * oc + 1];
    unsigned short* dst = wa + (size_t)(b * NOC + oc) * KTOT;
    const float* wsrc = f2w + (size_t)oc * KTOT;
    const float* bsrc = f2b + (size_t)oc * KTOT;
    #pragma unroll
    for (int s = 0; s < 9; ++s) {
        int rem = c * 9 + s;                 // index within the oc row of fc2
        float a = (rem >= 1152) ? a1 : a0;   // group = 2*oc + (rem>=PER)
        float v = a * wsrc[rem] + bsrc[rem];
        dst[s * NC + c] = f2bf(v);
    }
}

// ---------------- P4: x -> bf16 NHWC with zero halo ----------------
// grid (56 py, 32 b) x 256 threads; halo zeros come from the memset
__global__ void xpose_kernel(const float* __restrict__ x, unsigned short* __restrict__ xbt) {
    __shared__ unsigned short tile[NC][57];
    int py = blockIdx.x, b = blockIdx.y, t = threadIdx.x;
    const float* xs = x + (size_t)b * NC * NPIX + py * HWD;
    for (int i = 0; i < 56; ++i) {
        int lin = i * 256 + t;
        int c = lin / 56, px = lin % 56;
        tile[c][px] = f2bf(xs[(size_t)c * NPIX + px]);
    }
    __syncthreads();
    int cch = t & 31;          // channel chunk (8 ch = 16B)
    int pg  = t >> 5;          // pixel group
    for (int i = 0; i < 7; ++i) {
        int px = pg * 7 + i;
        u16x8 v;
        #pragma unroll
        for (int j = 0; j < 8; ++j) v[j] = tile[cch * 8 + j][px];
        *(u16x8*)(xbt + ((size_t)b * PPIX + (size_t)(1 + py) * PW + 1 + px) * NC + cch * 8) = v;
    }
}

// ---------------- main GEMM: implicit 9-shift conv ----------------
// per block: one batch, 128 oc x 128 pixels, K loop = 36 steps of 64 (s outer, c inner)
__global__ __launch_bounds__(256) void conv_gemm(
    const unsigned short* __restrict__ wa,   // [32][256][2304] bf16
    const unsigned short* __restrict__ xbt,  // [32][3364][256] bf16 (padded NHWC)
    float* __restrict__ out)                 // [32][256][3136]
{
    __shared__ __attribute__((aligned(16))) unsigned short Asm_[128 * 64];
    __shared__ __attribute__((aligned(16))) unsigned short Bsm_[128 * 64];
    const int nt = blockIdx.x, mt = blockIdx.y, b = blockIdx.z;
    const int t = threadIdx.x;
    const int w = t >> 6, l = t & 63;
    const int wm = w >> 1, wn = w & 1;

    f32x4 acc[4][4] = {};

    // staging constants: lane l stages 16B of row (w*32 + i*8 + (l>>3)),
    // logical k-chunk q is pre-swizzled so the lane-linear LDS dest equals
    // the swizzled layout phys(m,q) = m*128B + ((q ^ (m&7))*16B)
    const int srow = w * 32 + (l >> 3);
    const int sq   = (l & 7) ^ ((l >> 3) & 7);

    const unsigned short* waB = wa + (size_t)(b * NOC + mt * 128) * KTOT;
    const unsigned short* xbB = xbt + (size_t)b * PPIX * NC;

    for (int ks = 0; ks < 36; ++ks) {
        const int s  = ks >> 2;
        const int dy = s / 3 - 1, dx = s % 3 - 1;
        const int coff = (ks & 3) * 64 + sq * 8;   // channel offset for B
        // stage A tile (128 x 64)
        #pragma unroll
        for (int i = 0; i < 4; ++i) {
            int m = srow + i * 8;
            const unsigned short* src = waB + (size_t)m * KTOT + ks * 64 + sq * 8;
            __builtin_amdgcn_global_load_lds(
                (const __attribute__((address_space(1))) void*)src,
                (__attribute__((address_space(3))) void*)(Asm_ + (w * 32 + i * 8) * 64),
                16, 0, 0);
        }
        // stage B tile (128 pixels x 64 channels), shifted via halo layout
        #pragma unroll
        for (int i = 0; i < 4; ++i) {
            int n = srow + i * 8;
            int p = nt * 128 + n; if (p > NPIX - 1) p = NPIX - 1;
            int py = p / 56, px = p - py * 56;
            int pp = (py + dy + 1) * PW + (px + dx + 1);
            const unsigned short* src = xbB + (size_t)pp * NC + coff;
            __builtin_amdgcn_global_load_lds(
                (const __attribute__((address_space(1))) void*)src,
                (__attribute__((address_space(3))) void*)(Bsm_ + (w * 32 + i * 8) * 64),
                16, 0, 0);
        }
        __syncthreads();
        #pragma unroll
        for (int kk = 0; kk < 2; ++kk) {
            const int kq = kk * 4 + (l >> 4);   // logical 16B chunk along K
            bf16x8 af[4], bfr[4];
            #pragma unroll
            for (int i = 0; i < 4; ++i) {
                int m = wm * 64 + i * 16 + (l & 15);
                af[i]  = *(const bf16x8*)((const char*)Asm_ + m * 128 + ((kq ^ (m & 7)) * 16));
                int n = wn * 64 + i * 16 + (l & 15);
                bfr[i] = *(const bf16x8*)((const char*)Bsm_ + n * 128 + ((kq ^ (n & 7)) * 16));
            }
            #pragma unroll
            for (int i = 0; i < 4; ++i)
                #pragma unroll
                for (int j = 0; j < 4; ++j)
                    acc[i][j] = __builtin_amdgcn_mfma_f32_16x16x32_bf16(af[i], bfr[j], acc[i][j], 0, 0, 0);
        }
        __syncthreads();
    }

    // epilogue: D lane map col = l&15 (pixel), row = (l>>4)*4 + r (oc)
    const int mbase = mt * 128 + wm * 64;
    const int nbase = nt * 128 + wn * 64;
    #pragma unroll
    for (int i = 0; i < 4; ++i) {
        #pragma unroll
        for (int j = 0; j < 4; ++j) {
            int p = nbase + j * 16 + (l & 15);
            if (p < NPIX) {
                int oc = mbase + i * 16 + ((l >> 4) << 2);
                float* o = out + (size_t)(b * NOC + oc) * NPIX + p;
                #pragma unroll
                for (int r = 0; r < 4; ++r) o[(size_t)r * NPIX] = acc[i][j][r];
            }
        }
    }
}

extern "C" void kernel_launch(void* const* d_in, const int* in_sizes, int n_in,
                              void* d_out, int out_size, void* d_ws, size_t ws_size,
                              hipStream_t stream) {
    (void)in_sizes; (void)n_in; (void)out_size; (void)ws_size;
    const float* x   = (const float*)d_in[0];
    const float* rw  = (const float*)d_in[1];
    const float* rb  = (const float*)d_in[2];
    const float* f1w = (const float*)d_in[3];
    const float* f2w = (const float*)d_in[4];
    const float* f2b = (const float*)d_in[5];
    float* out = (float*)d_out;

    char* wsb = (char*)d_ws;
    unsigned short* xbt = (unsigned short*)wsb;
    unsigned short* wa  = (unsigned short*)(wsb + XBT_BYTES);
    float* gap = (float*)(wsb + XBT_BYTES + WA_BYTES);
    float* a2  = (float*)(wsb + XBT_BYTES + WA_BYTES + (size_t)NB * NC * 4);

    // zero the halo (whole xbt; interior overwritten by xpose_kernel)
    hipMemsetAsync(xbt, 0, XBT_BYTES, stream);
    xpose_kernel<<<dim3(56, 32), 256, 0, stream>>>(x, xbt);
    gap_kernel<<<dim3(2048), 256, 0, stream>>>(x, gap);
    se_kernel<<<dim3(1), 512, 0, stream>>>(gap, rw, rb, f1w, a2);
    wk_kernel<<<dim3(256, 32), 256, 0, stream>>>(a2, f2w, f2b, wa);
    conv_gemm<<<dim3(25, 2, 32), 256, 0, stream>>>(wa, xbt, out);
}

// Round 2
// 214.556 us; speedup vs baseline: 1.4071x; 1.4071x over previous
//
#include <hip/hip_runtime.h>
#include <hip/hip_bf16.h>
#include <stdint.h>

// ---------------- problem constants ----------------
#define NB   32
#define NC   256
#define NOC  256
#define HWD  56
#define NPIX 3136      // 56*56
#define PW   58        // padded row width
#define PPIX 3364      // 58*58
#define KTOT 2304      // 9 * 256
#define MOD  512       // fc1 out channels
#define GAPD 16

// workspace layout (bytes)
#define XBT_BYTES ((size_t)NB * PPIX * NC * 2)            // 55,115,776
#define WA_BYTES  ((size_t)NB * NOC * KTOT * 2)           // 37,748,736

typedef __bf16 bf16x8 __attribute__((ext_vector_type(8)));
typedef float  f32x4  __attribute__((ext_vector_type(4)));
typedef unsigned short u16x8 __attribute__((ext_vector_type(8)));

__device__ __forceinline__ unsigned short f2bf(float f) {
    union { float f; unsigned int u; } v; v.f = f;
    unsigned int u = v.u;
    return (unsigned short)((u + 0x7FFFu + ((u >> 16) & 1u)) >> 16);
}

// ---------------- P1: SE network (one block, 512 threads) ----------------
__global__ void se_kernel(const float* __restrict__ gap,
                          const float* __restrict__ rw, const float* __restrict__ rb,
                          const float* __restrict__ f1w, float* __restrict__ a2) {
    __shared__ float sgap[NB * NC];
    __shared__ float sg[NB * GAPD];
    int t = threadIdx.x; // 0..511
    #pragma unroll
    for (int i = 0; i < 16; ++i) sgap[i * 512 + t] = gap[i * 512 + t];
    __syncthreads();
    {
        int b = t >> 4, tt = t & 15;
        float s = rb[tt];
        for (int c = 0; c < NC; ++c) s += sgap[b * NC + c] * rw[tt * NC + c];
        sg[b * GAPD + tt] = s;
    }
    __syncthreads();
    for (int i = 0; i < 32; ++i) {
        int o = i * 512 + t;
        int b = o >> 9, m = o & 511;
        float s = 0.f;
        #pragma unroll
        for (int tt = 0; tt < GAPD; ++tt) s += sg[b * GAPD + tt] * f1w[m * GAPD + tt];
        a2[o] = 1.0f / (1.0f + __expf(-s));
    }
}

// ---------------- P2: per-batch conv weights, bf16, k = s*256+c ----------------
__global__ void wk_kernel(const float* __restrict__ a2,
                          const float* __restrict__ f2w, const float* __restrict__ f2b,
                          unsigned short* __restrict__ wa) {
    int oc = blockIdx.x, b = blockIdx.y, c = threadIdx.x;
    float a0 = a2[b * MOD + 2 * oc];
    float a1 = a2[b * MOD + 2 * oc + 1];
    unsigned short* dst = wa + (size_t)(b * NOC + oc) * KTOT;
    const float* wsrc = f2w + (size_t)oc * KTOT;
    const float* bsrc = f2b + (size_t)oc * KTOT;
    #pragma unroll
    for (int s = 0; s < 9; ++s) {
        int rem = c * 9 + s;
        float a = (rem >= 1152) ? a1 : a0;
        float v = a * wsrc[rem] + bsrc[rem];
        dst[s * NC + c] = f2bf(v);
    }
}

// ---------------- P3: zero the halo of xbt (3.7 MB instead of 55 MB memset) ----------------
__global__ void halo_kernel(unsigned short* __restrict__ xbt) {
    int b = blockIdx.x, t = threadIdx.x;
    unsigned short* xb = xbt + (size_t)b * PPIX * NC;
    u16x8 z = {};
    // top row (pix 0..57) and bottom row (pix 3306..3363): 2 * 58 * 32 chunks
    for (int i = t; i < 3712; i += 256) {
        int r = (i >= 1856) ? 1 : 0;
        int c = i - r * 1856;
        int pix = r * (57 * 58) + (c >> 5);
        *(u16x8*)(xb + (size_t)pix * NC + (c & 31) * 8) = z;
    }
    // side cols: rows 1..56, px 0 and 57
    for (int i = t; i < 3584; i += 256) {
        int row = 1 + (i >> 6);
        int side = (i >> 5) & 1;
        int pix = row * PW + side * 57;
        *(u16x8*)(xb + (size_t)pix * NC + (i & 31) * 8) = z;
    }
}

// ---------------- P4: x -> bf16 NHWC with halo, fused GAP partial sums ----------------
__global__ void xpose_kernel(const float* __restrict__ x, unsigned short* __restrict__ xbt,
                             float* __restrict__ gap) {
    __shared__ unsigned short tile[NC][57];
    int py = blockIdx.x, b = blockIdx.y, t = threadIdx.x;
    const float* xs = x + (size_t)b * NC * NPIX + py * HWD;
    for (int i = 0; i < 56; ++i) {
        int lin = i * 256 + t;
        int c = lin / 56, px = lin % 56;
        tile[c][px] = f2bf(xs[(size_t)c * NPIX + px]);
    }
    __syncthreads();
    // fused GAP: thread t = channel t sums its row of this py-slice
    {
        float s = 0.f;
        #pragma unroll
        for (int px = 0; px < 56; ++px) {
            union { unsigned int u; float f; } cv;
            cv.u = ((unsigned int)tile[t][px]) << 16;
            s += cv.f;
        }
        atomicAdd(&gap[b * NC + t], s * (1.0f / NPIX));
    }
    int cch = t & 31, pg = t >> 5;
    for (int i = 0; i < 7; ++i) {
        int px = pg * 7 + i;
        u16x8 v;
        #pragma unroll
        for (int j = 0; j < 8; ++j) v[j] = tile[cch * 8 + j][px];
        *(u16x8*)(xbt + ((size_t)b * PPIX + (size_t)(1 + py) * PW + 1 + px) * NC + cch * 8) = v;
    }
}

// ---------------- main GEMM: 256x256 tile, 8 waves, 4-slice pipeline ----------------
// K = 2304 = 72 phases of 32. Slice (p&3) holds A[256][32] + B[256][32], 32 KB.
// Prefetch distance 2 slices; counted vmcnt(8) (4 loads/thread/slice, 3 slices in flight).
#define SLICE_BYTES 32768
#define B_OFF 16384

#define PWAIT(N) do { asm volatile("s_waitcnt vmcnt(" #N ")" ::: "memory"); \
    __builtin_amdgcn_s_barrier(); __builtin_amdgcn_sched_barrier(0); } while (0)

__global__ __launch_bounds__(512, 2) void conv_gemm(
    const unsigned short* __restrict__ wa,   // [32][256][2304] bf16
    const unsigned short* __restrict__ xbt,  // [32][3364][256] bf16 (padded NHWC)
    float* __restrict__ out)                 // [32][256][3136]
{
    __shared__ __attribute__((aligned(16))) char lds[4 * SLICE_BYTES];  // 128 KB

    // XCD-aware bijective swizzle: 416 blocks = 8 XCD * 52; each XCD gets 4 whole batches
    const int bid = blockIdx.x;
    const int wg  = (bid & 7) * 52 + (bid >> 3);
    const int nt  = wg % 13, b = wg / 13;

    const int t = threadIdx.x;
    const int w = t >> 6, l = t & 63;
    const int wm = w >> 2, wn = w & 3;          // 2M x 4N waves, each 128x64

    const unsigned short* waB = wa + (size_t)b * NOC * KTOT;
    const unsigned short* xbB = xbt + (size_t)b * PPIX * NC;

    // ---- staging source addresses (m173 pattern: pre-swizzled global source,
    //      linear LDS dest).  1KB unit = 16 rows x 4 chunks of 16B;
    //      slot l -> row l>>2, phys chunk l&3, logical chunk q = (l&3)^((l>>3)&3)
    const int srow = l >> 2;
    const int sq   = (l & 3) ^ ((l >> 3) & 3);
    const unsigned short* pA0 = waB + (size_t)(w * 16 + srow) * KTOT + sq * 8;
    const unsigned short* pA1 = waB + (size_t)((w + 8) * 16 + srow) * KTOT + sq * 8;
    int pg0 = nt * 256 + (2 * w) * 16 + srow;     if (pg0 > NPIX - 1) pg0 = NPIX - 1;
    int pg1 = nt * 256 + (2 * w + 1) * 16 + srow; if (pg1 > NPIX - 1) pg1 = NPIX - 1;
    const int py0 = pg0 / 56, px0 = pg0 - py0 * 56;
    const int py1 = pg1 / 56, px1 = pg1 - py1 * 56;
    const unsigned short* pB0 = xbB + (size_t)((py0 + 1) * PW + (px0 + 1)) * NC + sq * 8;
    const unsigned short* pB1 = xbB + (size_t)((py1 + 1) * PW + (px1 + 1)) * NC + sq * 8;

    f32x4 acc[8][4] = {};

    auto issue = [&](int tp) {
        const int ss = tp & 3;
        char* sb = lds + ss * SLICE_BYTES;
        const int koff = tp * 32;                          // A: k runs straight through
        const int s9 = tp >> 3;
        const int dy = s9 / 3, dx = s9 - dy * 3;           // 0..2
        const int bsh = ((dy - 1) * PW + (dx - 1)) * NC + (tp & 7) * 32;
        __builtin_amdgcn_global_load_lds(
            (const __attribute__((address_space(1))) void*)(pA0 + koff),
            (__attribute__((address_space(3))) void*)(sb + w * 1024), 16, 0, 0);
        __builtin_amdgcn_global_load_lds(
            (const __attribute__((address_space(1))) void*)(pA1 + koff),
            (__attribute__((address_space(3))) void*)(sb + (w + 8) * 1024), 16, 0, 0);
        __builtin_amdgcn_global_load_lds(
            (const __attribute__((address_space(1))) void*)(pB0 + bsh),
            (__attribute__((address_space(3))) void*)(sb + B_OFF + (2 * w) * 1024), 16, 0, 0);
        __builtin_amdgcn_global_load_lds(
            (const __attribute__((address_space(1))) void*)(pB1 + bsh),
            (__attribute__((address_space(3))) void*)(sb + B_OFF + (2 * w + 1) * 1024), 16, 0, 0);
    };

    // ds_read: lane reads row = frag*16 + (l&15), chunk kq = l>>4 at phys chunk
    // kq ^ ((row>>1)&3) = kq ^ ((l>>1)&3)  -> lane-constant offset, 2-way banks (free)
    const int physq16 = (((l >> 4) ^ ((l >> 1) & 3)) << 4);
    const int arow = (l & 15) << 6;

    auto compute = [&](int p) {
        const char* sb = lds + (p & 3) * SLICE_BYTES;
        bf16x8 af[8], bfr[4];
        #pragma unroll
        for (int i = 0; i < 8; ++i)
            af[i] = *(const bf16x8*)(sb + wm * 8192 + i * 1024 + arow + physq16);
        #pragma unroll
        for (int j = 0; j < 4; ++j)
            bfr[j] = *(const bf16x8*)(sb + B_OFF + wn * 4096 + j * 1024 + arow + physq16);
        __builtin_amdgcn_s_setprio(1);
        #pragma unroll
        for (int i = 0; i < 8; ++i)
            #pragma unroll
            for (int j = 0; j < 4; ++j)
                acc[i][j] = __builtin_amdgcn_mfma_f32_16x16x32_bf16(af[i], bfr[j], acc[i][j], 0, 0, 0);
        __builtin_amdgcn_s_setprio(0);
    };

    // prologue: 2 slices in flight
    issue(0); issue(1);
    #pragma unroll 4
    for (int p = 0; p < 68; ++p) { issue(p + 2); PWAIT(8); compute(p); }
    issue(70); PWAIT(8); compute(68);
    issue(71); PWAIT(8); compute(69);
    PWAIT(4);  compute(70);
    PWAIT(0);  compute(71);

    // epilogue: D lane map col = l&15 (pixel), row = (l>>4)*4 + r (oc)
    const int ocb = wm * 128 + ((l >> 4) << 2);
    const int pxb = nt * 256 + wn * 64 + (l & 15);
    #pragma unroll
    for (int i = 0; i < 8; ++i) {
        #pragma unroll
        for (int j = 0; j < 4; ++j) {
            int p = pxb + j * 16;
            if (p < NPIX) {
                float* o = out + ((size_t)(b * NOC + ocb + i * 16)) * NPIX + p;
                o[0]        = acc[i][j][0];
                o[NPIX]     = acc[i][j][1];
                o[2 * NPIX] = acc[i][j][2];
                o[3 * NPIX] = acc[i][j][3];
            }
        }
    }
}

extern "C" void kernel_launch(void* const* d_in, const int* in_sizes, int n_in,
                              void* d_out, int out_size, void* d_ws, size_t ws_size,
                              hipStream_t stream) {
    (void)in_sizes; (void)n_in; (void)out_size; (void)ws_size;
    const float* x   = (const float*)d_in[0];
    const float* rw  = (const float*)d_in[1];
    const float* rb  = (const float*)d_in[2];
    const float* f1w = (const float*)d_in[3];
    const float* f2w = (const float*)d_in[4];
    const float* f2b = (const float*)d_in[5];
    float* out = (float*)d_out;

    char* wsb = (char*)d_ws;
    unsigned short* xbt = (unsigned short*)wsb;
    unsigned short* wa  = (unsigned short*)(wsb + XBT_BYTES);
    float* gap = (float*)(wsb + XBT_BYTES + WA_BYTES);
    float* a2  = (float*)(wsb + XBT_BYTES + WA_BYTES + (size_t)NB * NC * 4);

    hipMemsetAsync(gap, 0, (size_t)NB * NC * 4, stream);
    halo_kernel<<<dim3(32), 256, 0, stream>>>(xbt);
    xpose_kernel<<<dim3(56, 32), 256, 0, stream>>>(x, xbt, gap);
    se_kernel<<<dim3(1), 512, 0, stream>>>(gap, rw, rb, f1w, a2);
    wk_kernel<<<dim3(256, 32), 256, 0, stream>>>(a2, f2w, f2b, wa);
    conv_gemm<<<dim3(416), 512, 0, stream>>>(wa, xbt, out);
}